// Round 2
// baseline (21.857 us; speedup 1.0000x reference)
//
#include <hip/hip_runtime.h>
#include <cmath>

#define HDIM 128
typedef float f32x2 __attribute__((ext_vector_type(2)));

constexpr float EPSF = 1e-5f;
constexpr float K2L  = 2.8853900817779268f;   // 2*log2(e)
constexpr float L2E  = 1.4426950408889634f;   // log2(e)
constexpr float LN2  = 0.6931471805599453f;

__device__ inline float fast_rcp(float x) { return __builtin_amdgcn_rcpf(x); }

__device__ inline float fast_exp2(float x) {
#if __has_builtin(__builtin_amdgcn_exp2f)
    return __builtin_amdgcn_exp2f(x);
#else
    float r; asm("v_exp_f32 %0, %1" : "=v"(r) : "v"(x)); return r;
#endif
}

__device__ inline float fast_log2(float x) {
#if __has_builtin(__builtin_amdgcn_logf)
    return __builtin_amdgcn_logf(x);
#else
    float r; asm("v_log_f32 %0, %1" : "=v"(r) : "v"(x)); return r;
#endif
}

__device__ inline f32x2 pk_fma(f32x2 a, f32x2 b, f32x2 c) {
#if __has_builtin(__builtin_elementwise_fma)
    return __builtin_elementwise_fma(a, b, c);
#else
    f32x2 r; r.x = fmaf(a.x, b.x, c.x); r.y = fmaf(a.y, b.y, c.y); return r;
#endif
}

__device__ inline double wave_reduce(double v) {
    #pragma unroll
    for (int off = 32; off > 0; off >>= 1)
        v += __shfl_down(v, off, 64);
    return v;
}

// Raw-weight epilogue: u_t = ut, u_x = ux, u_xx = -2*uxxp  (no K2L residue)
__device__ inline void point_epilogue(float u, float ut, float ux, float uxxp,
                                      float x, float tgt,
                                      double& mspe, double& cal, double& bfly)
{
    // sigmoid + softplus from one exp2
    const float q  = fast_exp2(-fabsf(u) * L2E);           // e^{-|u|}
    const float rp = fast_rcp(1.f + q);
    const float s  = (u >= 0.f) ? rp : q * rp;             // sigmoid(u)
    const float w_log  = fmaxf(u, 0.f) + LN2 * fast_log2(1.f + q);
    const float w_tail = q * fmaf(-0.5f, q, 1.f);          // softplus(u), u << 0
    const float w  = (u < -9.f) ? w_tail : w_log;

    const float w_t  = s * ut;
    const float w_x  = s * ux;
    const float w_xx = fmaf(s * (1.f - s), ux * ux, -2.f * s * uxxp);

    const float pe = (w - tgt) * fast_rcp(tgt + EPSF);
    mspe += (double)pe * (double)pe;

    const float ctm = fmaxf(-w_t, 0.f);
    cal += (double)ctm * (double)ctm;

    const float invw = fast_rcp(w);
    const float a1 = fmaf(-0.5f * x * w_x, invw, 1.f);
    const float g  = fmaf(0.5f, w_xx,
                     fmaf(a1, a1, -0.25f * w_x * (invw + 0.25f)));
    const float btm = fmaxf(-g, 0.f);
    bfly += (double)btm * (double)btm;
}

__global__ __launch_bounds__(256, 4) void surf_loss_main(
    const float* __restrict__ tt, const float* __restrict__ xx,
    const float* __restrict__ tg,
    const float* __restrict__ W1, const float* __restrict__ b1,
    const float* __restrict__ W2, const float* __restrict__ b2,
    double* __restrict__ partials, int N)
{
    __shared__ double sred[3][4];
    const int tid = threadIdx.x;

    // Wave-uniform weight rows, read as float2 pairs (units i, i+1).
    const f32x2* __restrict__ A2 = (const f32x2*)(W1);          // row 0: A
    const f32x2* __restrict__ C2 = (const f32x2*)(W1 + HDIM);   // row 1: C
    const f32x2* __restrict__ B2 = (const f32x2*)(b1);
    const f32x2* __restrict__ V2 = (const f32x2*)(W2);
    const float b2v = b2[0];

    double mspe = 0.0, cal = 0.0, bfly = 0.0;

    for (int idx = blockIdx.x * 256 + tid; idx < N; idx += gridDim.x * 256) {
        const float t = tt[idx], x = xx[idx], tgt = tg[idx];
        const f32x2 t2 = {t, t};
        const f32x2 x2 = {x, x};
        f32x2 u2   = {b2v, 0.f};   // b2 folded into horizontal sum
        f32x2 ut2  = {0.f, 0.f};
        f32x2 ux2  = {0.f, 0.f};
        f32x2 uxx2 = {0.f, 0.f};
        #pragma unroll 8
        for (int i = 0; i < HDIM / 2; ++i) {
            const f32x2 a = A2[i];   // uniform -> SGPR pair
            const f32x2 c = C2[i];
            const f32x2 b = B2[i];
            const f32x2 v = V2[i];
            // one SGPR operand per instruction: mul, add, fma
            const f32x2 zc = x2 * c;
            const f32x2 zb = zc + b;
            const f32x2 z  = pk_fma(t2, a, zb);
            const f32x2 zp = z * K2L;                          // 2z*log2(e)
            f32x2 e;  e.x = fast_exp2(zp.x); e.y = fast_exp2(zp.y);
            f32x2 r;  r.x = fast_rcp(e.x + 1.f); r.y = fast_rcp(e.y + 1.f);
            const f32x2 th = pk_fma((f32x2){-2.f, -2.f}, r, (f32x2){1.f, 1.f});
            const f32x2 d  = pk_fma(-th, th, (f32x2){1.f, 1.f});
            const f32x2 wd = d * v;
            u2   = pk_fma(th, v, u2);
            ut2  = pk_fma(wd, a, ut2);
            ux2  = pk_fma(wd, c, ux2);
            const f32x2 wt  = wd * th;
            const f32x2 wtc = wt * c;
            uxx2 = pk_fma(wtc, c, uxx2);                       // +sum wd*th*c^2
        }
        const float u    = u2.x + u2.y;
        const float ut   = ut2.x + ut2.y;
        const float ux   = ux2.x + ux2.y;
        const float uxxp = uxx2.x + uxx2.y;
        point_epilogue(u, ut, ux, uxxp, x, tgt, mspe, cal, bfly);
    }

    double v0 = wave_reduce(mspe), v1 = wave_reduce(cal), v2 = wave_reduce(bfly);
    const int wid = tid >> 6, lane = tid & 63;
    if (lane == 0) { sred[0][wid] = v0; sred[1][wid] = v1; sred[2][wid] = v2; }
    __syncthreads();
    if (tid == 0) {
        double a = 0, b = 0, c = 0;
        #pragma unroll
        for (int wv = 0; wv < 4; ++wv) { a += sred[0][wv]; b += sred[1][wv]; c += sred[2][wv]; }
        partials[blockIdx.x * 3 + 0] = a;
        partials[blockIdx.x * 3 + 1] = b;
        partials[blockIdx.x * 3 + 2] = c;
    }
}

__global__ __launch_bounds__(256) void surf_loss_final(
    const double* __restrict__ partials, int nblocks, float* __restrict__ out, int N)
{
    const int tid = threadIdx.x;
    double a = 0, b = 0, c = 0;
    for (int i = tid; i < nblocks; i += 256) {
        a += partials[i * 3 + 0];
        b += partials[i * 3 + 1];
        c += partials[i * 3 + 2];
    }
    a = wave_reduce(a); b = wave_reduce(b); c = wave_reduce(c);
    __shared__ double sred[3][4];
    const int wid = tid >> 6, lane = tid & 63;
    if (lane == 0) { sred[0][wid] = a; sred[1][wid] = b; sred[2][wid] = c; }
    __syncthreads();
    if (tid == 0) {
        const double inv = 1.0 / (double)N;
        double s0 = 0, s1 = 0, s2 = 0;
        #pragma unroll
        for (int wv = 0; wv < 4; ++wv) { s0 += sred[0][wv]; s1 += sred[1][wv]; s2 += sred[2][wv]; }
        out[0] = (float)(s0 * inv);
        out[1] = (float)(s1 * inv);
        out[2] = (float)(s2 * inv);
    }
}

extern "C" void kernel_launch(void* const* d_in, const int* in_sizes, int n_in,
                              void* d_out, int out_size, void* d_ws, size_t ws_size,
                              hipStream_t stream) {
    const float* tt = (const float*)d_in[0];
    const float* xx = (const float*)d_in[1];
    const float* tg = (const float*)d_in[2];
    const float* W1 = (const float*)d_in[3];
    const float* b1 = (const float*)d_in[4];
    const float* W2 = (const float*)d_in[5];
    const float* b2 = (const float*)d_in[6];
    const int N = in_sizes[0];

    int blocks = (N + 255) / 256;
    if (blocks > 1024) blocks = 1024;
    while ((size_t)blocks * 3 * sizeof(double) > ws_size && blocks > 1) blocks >>= 1;

    double* partials = (double*)d_ws;
    surf_loss_main<<<blocks, 256, 0, stream>>>(tt, xx, tg, W1, b1, W2, b2, partials, N);
    surf_loss_final<<<1, 256, 0, stream>>>(partials, blocks, (float*)d_out, N);
}